// Round 6
// baseline (21.239 us; speedup 1.0000x reference)
//
#include <hip/hip_runtime.h>
#include <hip/hip_bf16.h>
#include <math.h>

// Two-dispatch PillarFeatureNet, fully inside MFMA k-space (k-slot map as R4):
//   k0-3 : raw features            x (W0+W4+W7, W1+W5+W8, W2+W6, W3)*s
//   k4-6 : -mean (masked)          x (W4,W5,W6)*s
//   k8-11: -cx_hi,-cx_lo,-cy_...   x (W7s,W7s,W8s,W8s)
//   k12-13: 1.0 (never masked)     x (tb_hi,tb_lo)   -> invalid rows = tb exactly
// Kernel A (1 wave): build per-lane B-fragments once -> d_ws (2 KB).
// Kernel B: 1 pillar per wave (40000 waves, max TLP); prologue = 2 frag loads
// (L2-hot) + wave-uniform s_loads of nv/coors + 1 float4 feature load.

#define NPIL  40000
#define WPB   4
#define BLOCK (WPB * 64)
#define NBLKB (NPIL / WPB)     // 10000 blocks, 1 pillar per wave

typedef float f32x16 __attribute__((ext_vector_type(16)));
typedef short bf16x8 __attribute__((ext_vector_type(8)));

union frag_u { bf16x8 h; int4 w; };

__device__ __forceinline__ int pk(float a, float b) {
    unsigned lo = (unsigned)__bfloat16_as_ushort(__float2bfloat16(a));
    unsigned hi = (unsigned)__bfloat16_as_ushort(__float2bfloat16(b));
    return (int)(lo | (hi << 16));
}
__device__ __forceinline__ float bfround(float x) {
    return __bfloat162float(__float2bfloat16(x));
}

template<int CTRL>
__device__ __forceinline__ float dpp_add(float x) {
    return x + __int_as_float(__builtin_amdgcn_update_dpp(
        0, __float_as_int(x), CTRL, 0xF, 0xF, true));
}
// sum over lanes 0..31 broadcast (lanes 32..63 irrelevant/garbage-safe)
__device__ __forceinline__ float lo32_sum(float x) {
    x = dpp_add<0x111>(x);   // row_shr:1
    x = dpp_add<0x112>(x);   // row_shr:2
    x = dpp_add<0x114>(x);   // row_shr:4
    x = dpp_add<0x118>(x);   // row_shr:8
    x = dpp_add<0x142>(x);   // row_bcast:15 -> lane31 = sum(0..31)
    return __int_as_float(__builtin_amdgcn_readlane(__float_as_int(x), 31));
}

__device__ __forceinline__ float vmax16(const f32x16& a) {
    float t0 = fmaxf(fmaxf(a[0],  a[1]),  a[2]);
    float t1 = fmaxf(fmaxf(a[3],  a[4]),  a[5]);
    float t2 = fmaxf(fmaxf(a[6],  a[7]),  a[8]);
    float t3 = fmaxf(fmaxf(a[9],  a[10]), a[11]);
    float t4 = fmaxf(fmaxf(a[12], a[13]), a[14]);
    float u0 = fmaxf(fmaxf(t0, t1), t2);
    float u1 = fmaxf(fmaxf(t3, t4), a[15]);
    return fmaxf(u0, u1);
}

// ---------------- Kernel A: build B-fragments into d_ws (once per call) ----
__global__ void pfn_prep_kernel(const float* __restrict__ Wm,
                                const float* __restrict__ gamma,
                                const float* __restrict__ beta,
                                const float* __restrict__ rmean,
                                const float* __restrict__ rvar,
                                int4* __restrict__ frag)     // [64][2]
{
    const int  lane = threadIdx.x & 63;
    const int  lo31 = lane & 31;
    const bool hih  = (lane >= 32);

    #pragma unroll
    for (int t = 0; t < 2; ++t) {
        const int uu = lo31 + t * 32;
        const float* w = Wm + uu * 9;
        const float s  = gamma[uu] * rsqrtf(rvar[uu] + 1e-3f);
        const float tb = beta[uu] - rmean[uu] * s;
        int4 r;
        if (!hih) {                       // lanes 0-31 carry k0-7 of column uu&31
            r.x = pk((w[0] + w[4] + w[7]) * s, (w[1] + w[5] + w[8]) * s);
            r.y = pk((w[2] + w[6]) * s,        w[3] * s);
            r.z = pk(w[4] * s,                 w[5] * s);
            r.w = pk(w[6] * s,                 0.0f);
        } else {                          // lanes 32-63 carry k8-15
            const float w7s = w[7] * s, w8s = w[8] * s;
            r.x = pk(w7s, w7s);
            r.y = pk(w8s, w8s);
            r.z = pk(tb,  tb - bfround(tb));   // (tb_hi, tb_lo)
            r.w = 0;
        }
        frag[lane * 2 + t] = r;
    }
}

// ---------------- Kernel B: 1 pillar per wave ------------------------------
__global__ __launch_bounds__(BLOCK)
void pfn_main_kernel(const float* __restrict__ features,   // [N,32,4]
                     const int*   __restrict__ num_voxels, // [N]
                     const int*   __restrict__ coors,      // [N,4]
                     const int4*  __restrict__ frag,       // [64][2] from kernel A
                     float* __restrict__ out)               // [N,64]
{
    const int  lane = threadIdx.x & 63;
    const int  wid  = threadIdx.x >> 6;
    const int  lo31 = lane & 31;
    const bool hih  = (lane >= 32);

    const int n = blockIdx.x * WPB + wid;      // pillar id, WAVE-UNIFORM scalar

    // featherweight prologue: 2 coalesced frag loads (L2-hot 2 KB) ...
    frag_u bf0, bf1;
    bf0.w = frag[lane * 2 + 0];
    bf1.w = frag[lane * 2 + 1];
    // ... wave-uniform scalar loads ...
    const int  snv = num_voxels[n];                                   // s_load
    const int2 cc  = *reinterpret_cast<const int2*>(coors + n * 4 + 2); // s_load_dwordx2
    // ... and one float4 of features (lanes 32-63 duplicate 0-31: same cachelines)
    const float4 q = *reinterpret_cast<const float4*>(
        features + (size_t)n * 128 + lo31 * 4);

    // pillar mean over all 32 rows (reference: full sum / nv)
    const float S0 = lo32_sum(q.x);
    const float S1 = lo32_sum(q.y);
    const float S2 = lo32_sum(q.z);
    const float rn = __builtin_amdgcn_rcpf((float)snv);
    const float cx = (float)cc.y * 0.2f + 0.1f;
    const float cy = (float)cc.x * 0.2f + (0.1f - 40.0f);

    const int ONE2 = 0x3F803F80;               // pack(1.0bf, 1.0bf)
    const int f01 = pk(q.x, q.y);
    const int f23 = pk(q.z, q.w);
    const int mxy = pk(-S0 * rn, -S1 * rn);
    const int mz0 = pk(-S2 * rn, 0.0f);
    const int cxw = pk(-cx, -cx - bfround(-cx));
    const int cyw = pk(-cy, -cy - bfround(-cy));

    const bool valid = (lo31 < snv);
    const int  inv2  = hih ? ONE2 : 0;
    int w0 = hih ? cxw  : f01;  w0 = valid ? w0 : 0;
    int w1 = hih ? cyw  : f23;  w1 = valid ? w1 : 0;
    int w2 = hih ? ONE2 : mxy;  w2 = valid ? w2 : inv2;   // k12/13 never masked
    int w3 = hih ? 0    : mz0;  w3 = valid ? w3 : 0;
    frag_u af; af.w = make_int4(w0, w1, w2, w3);

    f32x16 z;
    #pragma unroll
    for (int i = 0; i < 16; ++i) z[i] = 0.0f;
    const f32x16 a0 = __builtin_amdgcn_mfma_f32_32x32x16_bf16(af.h, bf0.h, z, 0, 0, 0);
    const f32x16 a1 = __builtin_amdgcn_mfma_f32_32x32x16_bf16(af.h, bf1.h, z, 0, 0, 0);

    // max over 32 rows: per-lane 16, one lane^32 exchange (send partner's half)
    const float m0 = vmax16(a0);
    const float m1 = vmax16(a1);
    const float got  = __shfl_xor(hih ? m0 : m1, 32, 64);
    const float mine = hih ? m1 : m0;
    const float r = fmaxf(fmaxf(mine, got), 0.0f);   // relu folded into max

    out[(size_t)n * 64 + lane] = r;
}

extern "C" void kernel_launch(void* const* d_in, const int* in_sizes, int n_in,
                              void* d_out, int out_size, void* d_ws, size_t ws_size,
                              hipStream_t stream) {
    const float* features   = (const float*)d_in[0];
    const int*   num_voxels = (const int*)  d_in[1];
    const int*   coors      = (const int*)  d_in[2];
    const float* Wm         = (const float*)d_in[3];
    const float* gamma      = (const float*)d_in[4];
    const float* beta       = (const float*)d_in[5];
    const float* rmean      = (const float*)d_in[6];
    const float* rvar       = (const float*)d_in[7];
    float*       out        = (float*)d_out;
    int4*        frag       = (int4*)d_ws;

    hipLaunchKernelGGL(pfn_prep_kernel, dim3(1), dim3(64), 0, stream,
                       Wm, gamma, beta, rmean, rvar, frag);
    hipLaunchKernelGGL(pfn_main_kernel, dim3(NBLKB), dim3(BLOCK), 0, stream,
                       features, num_voxels, coors, frag, out);
}

// Round 7
// 16.238 us; speedup vs baseline: 1.3080x; 1.3080x over previous
//
#include <hip/hip_runtime.h>
#include <hip/hip_bf16.h>
#include <math.h>

// PillarFeatureNet fully inside MFMA k-space (k-slot map):
//   k0-3 : raw features            x (W0+W4+W7, W1+W5+W8, W2+W6, W3)*s
//   k4-6 : -mean (masked)          x (W4,W5,W6)*s
//   k8-11: -cx_hi,-cx_lo,-cy_hi,lo x (W7s,W7s,W8s,W8s)
//   k12-13: 1.0 (never masked)     x (tb_hi,tb_lo)   -> invalid rows = tb exactly
// R7 = R4 structure (8 contiguous pillars/wave, 1250 blocks, all loads issued
// up front) + per-BLOCK LDS share of the B-fragment build (wave 0 builds once,
// 4 waves consume) -> removes the redundant ~1000cy per-wave prologue.

#define NPIL  40000
#define NITER 8
#define WPB   4
#define BLOCK (WPB * 64)
#define NBLK  (NPIL / (WPB * NITER))   // 1250

typedef float f32x16 __attribute__((ext_vector_type(16)));
typedef short bf16x8 __attribute__((ext_vector_type(8)));

union frag_u { bf16x8 h; int4 w; };

__device__ __forceinline__ int pk(float a, float b) {
    unsigned lo = (unsigned)__bfloat16_as_ushort(__float2bfloat16(a));
    unsigned hi = (unsigned)__bfloat16_as_ushort(__float2bfloat16(b));
    return (int)(lo | (hi << 16));
}
__device__ __forceinline__ float bfround(float x) {
    return __bfloat162float(__float2bfloat16(x));
}

template<int CTRL>
__device__ __forceinline__ float dpp_add(float x) {
    return x + __int_as_float(__builtin_amdgcn_update_dpp(
        0, __float_as_int(x), CTRL, 0xF, 0xF, true));
}
// sum over lanes 0..31, broadcast (reference mean = full 32-row sum / nv)
__device__ __forceinline__ float lo32_sum(float x) {
    x = dpp_add<0x111>(x);   // row_shr:1
    x = dpp_add<0x112>(x);   // row_shr:2
    x = dpp_add<0x114>(x);   // row_shr:4
    x = dpp_add<0x118>(x);   // row_shr:8
    x = dpp_add<0x142>(x);   // row_bcast:15 -> lane31 = sum(0..31)
    return __int_as_float(__builtin_amdgcn_readlane(__float_as_int(x), 31));
}

__device__ __forceinline__ float vmax16(const f32x16& a) {   // max3-fusable tree
    float t0 = fmaxf(fmaxf(a[0],  a[1]),  a[2]);
    float t1 = fmaxf(fmaxf(a[3],  a[4]),  a[5]);
    float t2 = fmaxf(fmaxf(a[6],  a[7]),  a[8]);
    float t3 = fmaxf(fmaxf(a[9],  a[10]), a[11]);
    float t4 = fmaxf(fmaxf(a[12], a[13]), a[14]);
    float u0 = fmaxf(fmaxf(t0, t1), t2);
    float u1 = fmaxf(fmaxf(t3, t4), a[15]);
    return fmaxf(u0, u1);
}

__global__ __launch_bounds__(BLOCK, 4)
void pfn_mfma_kernel(const float* __restrict__ features,   // [N,32,4]
                     const int*   __restrict__ num_voxels, // [N]
                     const int*   __restrict__ coors,      // [N,4]
                     const float* __restrict__ Wm,         // [64,9]
                     const float* __restrict__ gamma,
                     const float* __restrict__ beta,
                     const float* __restrict__ rmean,
                     const float* __restrict__ rvar,
                     float* __restrict__ out)               // [N,64]
{
    __shared__ int4 sfrag0[64];   // 16B stride -> conflict-free ds_read_b128
    __shared__ int4 sfrag1[64];

    const int  lane = threadIdx.x & 63;
    const int  wid  = threadIdx.x >> 6;
    const int  lo31 = lane & 31;
    const bool hih  = (lane >= 32);

    const int p0 = (blockIdx.x * WPB + wid) * NITER;   // 8 contiguous pillars

    // ---- issue ALL per-wave memory FIRST (latency hides under build+barrier) ----
    const float* fbase = features + (size_t)p0 * 128 + lo31 * 4;
    float4 qv[NITER];
    #pragma unroll
    for (int j = 0; j < NITER; ++j)
        qv[j] = *reinterpret_cast<const float4*>(fbase + (size_t)j * 128);
    const int  li  = (lane < NITER) ? lane : (NITER - 1);
    const int  nv8 = num_voxels[p0 + li];                                   // lane j -> pillar j
    const int2 cc8 = *reinterpret_cast<const int2*>(coors + (p0 + li) * 4 + 2);

    // ---- wave 0 builds the per-lane B-fragments ONCE per block ----
    if (wid == 0) {
        #pragma unroll
        for (int t = 0; t < 2; ++t) {
            const int uu = lo31 + t * 32;
            const float* w = Wm + uu * 9;
            const float s  = gamma[uu] * rsqrtf(rvar[uu] + 1e-3f);
            const float tb = beta[uu] - rmean[uu] * s;
            int4 r;
            if (!hih) {                       // lanes 0-31: k0-7 chunk of column uu&31
                r.x = pk((w[0] + w[4] + w[7]) * s, (w[1] + w[5] + w[8]) * s);
                r.y = pk((w[2] + w[6]) * s,        w[3] * s);
                r.z = pk(w[4] * s,                 w[5] * s);
                r.w = pk(w[6] * s,                 0.0f);
            } else {                          // lanes 32-63: k8-15 chunk
                const float w7s = w[7] * s, w8s = w[8] * s;
                r.x = pk(w7s, w7s);
                r.y = pk(w8s, w8s);
                r.z = pk(tb,  tb - bfround(tb));   // (tb_hi, tb_lo)
                r.w = 0;
            }
            if (t == 0) sfrag0[lane] = r; else sfrag1[lane] = r;
        }
    }
    __syncthreads();   // also drains the prefetched VMEM during the wait

    frag_u bf0, bf1;
    bf0.w = sfrag0[lane];
    bf1.w = sfrag1[lane];

    f32x16 z;
    #pragma unroll
    for (int i = 0; i < 16; ++i) z[i] = 0.0f;

    const int ONE2 = 0x3F803F80;                 // pack(1.0bf, 1.0bf)
    const int inv2 = hih ? ONE2 : 0;

    #pragma unroll
    for (int j = 0; j < NITER; ++j) {
        const int   snv = __builtin_amdgcn_readlane(nv8,   j);
        const int   sc2 = __builtin_amdgcn_readlane(cc8.x, j);
        const int   sc3 = __builtin_amdgcn_readlane(cc8.y, j);
        const float4 q  = qv[j];

        // pillar mean over all 32 rows (reference: full sum / nv)
        const float S0 = lo32_sum(q.x);
        const float S1 = lo32_sum(q.y);
        const float S2 = lo32_sum(q.z);
        const float rn = __builtin_amdgcn_rcpf((float)snv);   // |err|~1e-7 << bf16 lsb
        const float cx = (float)sc3 * 0.2f + 0.1f;
        const float cy = (float)sc2 * 0.2f + (0.1f - 40.0f);

        const int f01 = pk(q.x, q.y);
        const int f23 = pk(q.z, q.w);
        const int mxy = pk(-S0 * rn, -S1 * rn);
        const int mz0 = pk(-S2 * rn, 0.0f);
        const int cxw = pk(-cx, -cx - bfround(-cx));          // exact f32 split
        const int cyw = pk(-cy, -cy - bfround(-cy));

        const bool valid = (lo31 < snv);
        int w0 = hih ? cxw  : f01;  w0 = valid ? w0 : 0;
        int w1 = hih ? cyw  : f23;  w1 = valid ? w1 : 0;
        int w2 = hih ? ONE2 : mxy;  w2 = valid ? w2 : inv2;   // k12/13 never masked
        int w3 = hih ? 0    : mz0;  w3 = valid ? w3 : 0;
        frag_u af; af.w = make_int4(w0, w1, w2, w3);

        const f32x16 a0 = __builtin_amdgcn_mfma_f32_32x32x16_bf16(af.h, bf0.h, z, 0, 0, 0);
        const f32x16 a1 = __builtin_amdgcn_mfma_f32_32x32x16_bf16(af.h, bf1.h, z, 0, 0, 0);

        // max over 32 rows: per-lane 16, one lane^32 exchange (send partner's half)
        const float m0 = vmax16(a0);
        const float m1 = vmax16(a1);
        const float got  = __shfl_xor(hih ? m0 : m1, 32, 64);
        const float mine = hih ? m1 : m0;
        const float r = fmaxf(fmaxf(mine, got), 0.0f);   // relu folded into max

        out[(size_t)(p0 + j) * 64 + lane] = r;
    }
}

extern "C" void kernel_launch(void* const* d_in, const int* in_sizes, int n_in,
                              void* d_out, int out_size, void* d_ws, size_t ws_size,
                              hipStream_t stream) {
    const float* features   = (const float*)d_in[0];
    const int*   num_voxels = (const int*)  d_in[1];
    const int*   coors      = (const int*)  d_in[2];
    const float* Wm         = (const float*)d_in[3];
    const float* gamma      = (const float*)d_in[4];
    const float* beta       = (const float*)d_in[5];
    const float* rmean      = (const float*)d_in[6];
    const float* rvar       = (const float*)d_in[7];
    float*       out        = (float*)d_out;

    hipLaunchKernelGGL(pfn_mfma_kernel, dim3(NBLK), dim3(BLOCK), 0, stream,
                       features, num_voxels, coors, Wm, gamma, beta, rmean, rvar, out);
}